// Round 26
// baseline (93.223 us; speedup 1.0000x reference)
//
#include <hip/hip_runtime.h>
#include <hip/hip_bf16.h>
#include <hip/hip_fp16.h>

#define N_NODES 12000
#define N_EDGES 384000
#define F_IN 512
#define H 64
#define C_CLS 7
#define KTERMS 16
#define PAD 96
#define CSTR 32      // cur stride (ints): one 128B line per node (fill contention-free)
#define MOM_BLKS 768
#define MSTR 1040    // doubles per M copy: 1024 M + 16 m0
#define GEMM_BLKS 188   // 188 x 64-row MFMA tiles (12032 >= 12000, guarded)
#define FILL_BLKS 324

typedef __attribute__((ext_vector_type(8))) short bf16x8;
typedef __attribute__((ext_vector_type(4))) float f32x4;

__device__ __forceinline__ float wred_f(float x) {
    #pragma unroll
    for (int o = 32; o > 0; o >>= 1) x += __shfl_xor(x, o);
    return x;
}

// ---------------- k0: W1 -> transposed bf16 hi/lo split; zero cur lines + M8
__global__ __launch_bounds__(256) void init_k(const float* __restrict__ W1,
                                              unsigned short* __restrict__ w1Th,
                                              unsigned short* __restrict__ w1Tl,
                                              int* __restrict__ cur,
                                              double* __restrict__ M8) {
    int i = blockIdx.x * 256 + threadIdx.x;    // 128*256 = 32768 threads
    if (i < 64 * 512) {
        int n = i >> 9, k = i & 511;
        float v = W1[k * 64 + n];              // W1T[n][k] = W1[k][n]
        unsigned xb = __float_as_uint(v);
        float hf = __uint_as_float(xb & 0xffff0000u);
        w1Th[i] = (unsigned short)(xb >> 16);
        w1Tl[i] = (unsigned short)(__float_as_uint(v - hf) >> 16);
    }
    if (i < N_NODES) cur[i * CSTR] = 0;
    if (i < 8 * MSTR) M8[i] = 0.0;
}

// ---------------- k1: gemm1 via bf16-split MFMA; OUTPUT IN FP16 || CSR fill
__global__ __launch_bounds__(256) void k1_gemm_fill(const float* __restrict__ x,
                                                    const unsigned short* __restrict__ w1Th,
                                                    const unsigned short* __restrict__ w1Tl,
                                                    const int* __restrict__ ei,
                                                    __half* __restrict__ hbufH,
                                                    int* __restrict__ cur,
                                                    int* __restrict__ csrc) {
    const int b = blockIdx.x, t = threadIdx.x;
    if (b < GEMM_BLKS) {
        __shared__ unsigned short wh[64 * 72];    // [n][k-chunk 64], stride 72 shorts
        __shared__ unsigned short wl[64 * 72];
        const int l = t & 63, w = t >> 6;
        const int lm = l & 15, lk = l >> 4;
        const int i0 = b * 64;
        const int arow = min(i0 + w * 16 + lm, N_NODES - 1);
        const float* xrow = x + (size_t)arow * F_IN;
        f32x4 acc[4];
        #pragma unroll
        for (int c = 0; c < 4; ++c) acc[c] = (f32x4){0.f, 0.f, 0.f, 0.f};
        for (int kc = 0; kc < 8; ++kc) {
            #pragma unroll
            for (int q = 0; q < 2; ++q) {
                int idx = t + q * 256;
                int n = idx >> 3, kg = idx & 7;
                *(uint4*)(&wh[n * 72 + kg * 8]) =
                    *(const uint4*)(w1Th + n * 512 + kc * 64 + kg * 8);
                *(uint4*)(&wl[n * 72 + kg * 8]) =
                    *(const uint4*)(w1Tl + n * 512 + kc * 64 + kg * 8);
            }
            __syncthreads();
            #pragma unroll
            for (int ks = 0; ks < 2; ++ks) {
                float4 v0 = *(const float4*)(xrow + kc * 64 + ks * 32 + lk * 8);
                float4 v1 = *(const float4*)(xrow + kc * 64 + ks * 32 + lk * 8 + 4);
                float xv[8] = {v0.x, v0.y, v0.z, v0.w, v1.x, v1.y, v1.z, v1.w};
                bf16x8 ah, al;
                #pragma unroll
                for (int j = 0; j < 8; ++j) {
                    unsigned xb = __float_as_uint(xv[j]);
                    float hf = __uint_as_float(xb & 0xffff0000u);
                    ah[j] = (short)(xb >> 16);
                    al[j] = (short)(__float_as_uint(xv[j] - hf) >> 16);
                }
                #pragma unroll
                for (int c = 0; c < 4; ++c) {
                    bf16x8 bh = *(const bf16x8*)(&wh[(c * 16 + lm) * 72 + ks * 32 + lk * 8]);
                    bf16x8 bl = *(const bf16x8*)(&wl[(c * 16 + lm) * 72 + ks * 32 + lk * 8]);
                    acc[c] = __builtin_amdgcn_mfma_f32_16x16x32_bf16(ah, bh, acc[c], 0, 0, 0);
                    acc[c] = __builtin_amdgcn_mfma_f32_16x16x32_bf16(ah, bl, acc[c], 0, 0, 0);
                    acc[c] = __builtin_amdgcn_mfma_f32_16x16x32_bf16(al, bh, acc[c], 0, 0, 0);
                }
            }
            __syncthreads();
        }
        #pragma unroll
        for (int c = 0; c < 4; ++c) {
            #pragma unroll
            for (int r = 0; r < 4; ++r) {
                int row = i0 + w * 16 + lk * 4 + r;
                if (row < N_NODES)
                    hbufH[(size_t)row * H + c * 16 + lm] = __float2half(acc[c][r]);
            }
        }
    } else {
        for (int e = (b - GEMM_BLKS) * 256 + t; e < N_EDGES; e += FILL_BLKS * 256) {
            int s = ei[e];
            int d = ei[N_EDGES + e];
            int pos = atomicAdd(&cur[d * CSTR], 1);
            if (pos < PAD) csrc[d * PAD + pos] = s;   // overflow guard
        }
    }
}

// ---------------- k2: agg1 = relu((Â @ hbuf) + b1)
//   2 nodes/block, 2 waves per node (stride-2 half edge ranges) -> chain halved
__global__ __launch_bounds__(256) void agg1_k(const __half* __restrict__ hbufH,
                                              const float* __restrict__ b1,
                                              const int* __restrict__ cur,
                                              const int* __restrict__ csrc,
                                              __half* __restrict__ h1H) {
    __shared__ int2 sPair[2 * PAD];
    __shared__ int sDeg[2];
    __shared__ float sIsd[2];
    __shared__ float gpart[2 * 64];
    const int t = threadIdx.x, f = t & 63, w = t >> 6;
    const int n = w >> 1, hh = w & 1;
    const int base = blockIdx.x * 2;           // 6000 blocks
    if (t < 2) {
        int d = cur[(base + t) * CSTR];
        sDeg[t] = min(d, PAD);
        sIsd[t] = rsqrtf((float)d + 1.f);
    }
    __syncthreads();
    for (int idx = t; idx < 2 * PAD; idx += 256) {
        int nn = idx / PAD, e = idx - nn * PAD;
        if (e < sDeg[nn]) {
            int s = csrc[(base + nn) * PAD + e];
            sPair[idx] = make_int2(s, __float_as_int(rsqrtf((float)cur[s * CSTR] + 1.f)));
        }
    }
    __syncthreads();
    const int i = base + n;
    const int deg = sDeg[n];
    const float isd = sIsd[n];
    const int2* pp = sPair + n * PAD;
    float acc = 0.f;
    int e = hh;
    for (; e + 14 < deg; e += 16) {            // 8 edges/iter at stride 2
        float part = 0.f;
        #pragma unroll
        for (int u = 0; u < 8; ++u) {
            int2 p = pp[e + 2 * u];
            part += __half2float(hbufH[p.x * H + f]) * __int_as_float(p.y);
        }
        acc += part;
    }
    for (; e < deg; e += 2) {
        int2 p = pp[e];
        acc += __half2float(hbufH[p.x * H + f]) * __int_as_float(p.y);
    }
    if (hh == 1) gpart[n * 64 + f] = acc;
    __syncthreads();
    if (hh == 0) {
        float tot = acc + gpart[n * 64 + f];
        float res = (tot + __half2float(hbufH[i * H + f]) * isd) * isd + b1[f];
        h1H[i * H + f] = __float2half(fmaxf(res, 0.f));
    }
}

// ---------------- k3: agg2 = (Â @ h1) @ W2 + b2, + cosine score  [split-wave]
__global__ __launch_bounds__(256) void agg2_k(const __half* __restrict__ h1H,
                                              const float* __restrict__ W2,
                                              const float* __restrict__ b2,
                                              const float* __restrict__ aux,
                                              const int* __restrict__ cur,
                                              const int* __restrict__ csrc,
                                              __half* __restrict__ h2H,
                                              float* __restrict__ score) {
    __shared__ float w2s[64 * 64];
    __shared__ int2 sPair[2 * PAD];
    __shared__ int sDeg[2];
    __shared__ float sIsd[2];
    __shared__ float anorm[64];
    __shared__ float gpart[2 * 64];
    __shared__ float gsh[2 * 64];
    const int t = threadIdx.x, f = t & 63, w = t >> 6;
    const int n = w >> 1, hh = w & 1;
    const int base = blockIdx.x * 2;
    #pragma unroll
    for (int q = 0; q < 4; ++q) {
        int idx = t + q * 256;
        int r = idx >> 4, c4 = idx & 15;
        *(float4*)(&w2s[r * 64 + c4 * 4]) = *(const float4*)(W2 + r * H + c4 * 4);
    }
    if (t < 2) {
        int d = cur[(base + t) * CSTR];
        sDeg[t] = min(d, PAD);
        sIsd[t] = rsqrtf((float)d + 1.f);
    }
    if (t < 64) {
        float av = aux[t];
        anorm[t] = av * rsqrtf(fmaxf(wred_f(av * av), 1e-24f));
    }
    __syncthreads();
    for (int idx = t; idx < 2 * PAD; idx += 256) {
        int nn = idx / PAD, e = idx - nn * PAD;
        if (e < sDeg[nn]) {
            int s = csrc[(base + nn) * PAD + e];
            sPair[idx] = make_int2(s, __float_as_int(rsqrtf((float)cur[s * CSTR] + 1.f)));
        }
    }
    __syncthreads();
    const int i = base + n;
    const int deg = sDeg[n];
    const float isd = sIsd[n];
    const int2* pp = sPair + n * PAD;
    float acc = 0.f;
    int e = hh;
    for (; e + 14 < deg; e += 16) {
        float part = 0.f;
        #pragma unroll
        for (int u = 0; u < 8; ++u) {
            int2 p = pp[e + 2 * u];
            part += __half2float(h1H[p.x * H + f]) * __int_as_float(p.y);
        }
        acc += part;
    }
    for (; e < deg; e += 2) {
        int2 p = pp[e];
        acc += __half2float(h1H[p.x * H + f]) * __int_as_float(p.y);
    }
    if (hh == 1) gpart[n * 64 + f] = acc;
    __syncthreads();
    if (hh == 0) {
        float tot = acc + gpart[n * 64 + f];
        float g = (tot + __half2float(h1H[i * H + f]) * isd) * isd;
        gsh[n * 64 + f] = g;
        __builtin_amdgcn_wave_barrier();
        float hv = b2[f];
        #pragma unroll 16
        for (int k = 0; k < 64; ++k) hv += gsh[n * 64 + k] * w2s[k * 64 + f];
        h2H[i * H + f] = __float2half(hv);
        float dp = wred_f(hv * anorm[f]);
        float nn2 = wred_f(hv * hv);
        if (f == 0) score[i] = dp / fmaxf(sqrtf(nn2), 1e-8f);
    }
}

// ---------------- k4: moments, 768 blocks, striped 8-copy atomic flush [fp16 h2]
__global__ __launch_bounds__(256) void momden_k(const __half* __restrict__ h2H,
                                                const float* __restrict__ score,
                                                double* __restrict__ M8) {
    const int t = threadIdx.x, f = t & 63, g = t >> 6;
    float accM[KTERMS], accD[KTERMS];
    #pragma unroll
    for (int k = 0; k < KTERMS; ++k) { accM[k] = 0.f; accD[k] = 0.f; }
    for (int j = blockIdx.x * 4 + g; j < N_NODES; j += MOM_BLKS * 4) {
        float sj = score[j];
        float wj = expf(-sj * sj);
        float hv = __half2float(h2H[j * H + f]);
        float tm = wj * hv, td = wj;
        #pragma unroll
        for (int k = 0; k < KTERMS; ++k) {
            accM[k] += tm; tm *= sj;
            accD[k] += td; td *= sj;
        }
    }
    __shared__ float Msh[4 * KTERMS * 64];
    __shared__ float Dsh[4 * KTERMS];
    #pragma unroll
    for (int k = 0; k < KTERMS; ++k) Msh[(g * KTERMS + k) * 64 + f] = accM[k];
    if (f == 0) {
        #pragma unroll
        for (int k = 0; k < KTERMS; ++k) Dsh[g * KTERMS + k] = accD[k];
    }
    __syncthreads();
    double* Mc = M8 + (size_t)(blockIdx.x & 7) * MSTR;
    for (int idx = t; idx < KTERMS * 64; idx += 256) {
        int k = idx >> 6, ff = idx & 63;
        float sum = Msh[(0 * KTERMS + k) * 64 + ff] + Msh[(1 * KTERMS + k) * 64 + ff]
                  + Msh[(2 * KTERMS + k) * 64 + ff] + Msh[(3 * KTERMS + k) * 64 + ff];
        unsafeAtomicAdd(&Mc[idx], (double)sum);
    }
    if (t < KTERMS) {
        float sum = Dsh[t] + Dsh[KTERMS + t] + Dsh[2 * KTERMS + t] + Dsh[3 * KTERMS + t];
        unsafeAtomicAdd(&Mc[1024 + t], (double)sum);
    }
}

// ---------------- k5: z + concat classifier (sums the 8 M copies) [fp16 h2]
__global__ __launch_bounds__(256) void final_k(const __half* __restrict__ h2H,
                                               const float* __restrict__ score,
                                               const double* __restrict__ M8,
                                               const float* __restrict__ clfW,
                                               const float* __restrict__ clfb,
                                               float* __restrict__ out) {
    __shared__ float Ms[KTERMS * 64];
    __shared__ float m0s[KTERMS];
    __shared__ float cw[128 * C_CLS];
    __shared__ float cb[8];
    __shared__ float zh[4 * 128];
    const int t = threadIdx.x, f = t & 63, w = t >> 6;
    for (int idx = t; idx < KTERMS * 64; idx += 256) {
        double s = 0.0;
        #pragma unroll
        for (int c = 0; c < 8; ++c) s += M8[(size_t)c * MSTR + idx];
        Ms[idx] = (float)s;
    }
    if (t < KTERMS) {
        double s = 0.0;
        #pragma unroll
        for (int c = 0; c < 8; ++c) s += M8[(size_t)c * MSTR + 1024 + t];
        m0s[t] = (float)s;
    }
    for (int idx = t; idx < 128 * C_CLS; idx += 256) cw[idx] = clfW[idx];
    if (t < C_CLS) cb[t] = clfb[t];
    __syncthreads();
    const int base = blockIdx.x * 16;
    for (int q = 0; q < 4; ++q) {
        int i = base + q * 4 + w;
        float s = score[i];
        float c = expf(-s * s);
        float t2 = 2.f * s;
        float num = 0.f, den = 0.f;
        #pragma unroll
        for (int k = 0; k < KTERMS; ++k) {
            num += c * Ms[k * 64 + f];
            den += c * m0s[k];
            c *= t2 * (1.0f / (float)(k + 1));
        }
        zh[w * 128 + f] = __half2float(h2H[i * H + f]);
        zh[w * 128 + 64 + f] = num / den;
        __builtin_amdgcn_wave_barrier();
        if (f < C_CLS) {
            float o = cb[f];
            #pragma unroll 8
            for (int u = 0; u < 128; ++u) o += zh[w * 128 + u] * cw[u * C_CLS + f];
            out[(size_t)i * C_CLS + f] = o;
        }
        __builtin_amdgcn_wave_barrier();
    }
}

// ---------------- launch
extern "C" void kernel_launch(void* const* d_in, const int* in_sizes, int n_in,
                              void* d_out, int out_size, void* d_ws, size_t ws_size,
                              hipStream_t stream) {
    (void)in_sizes; (void)n_in; (void)out_size; (void)ws_size;
    const float* x    = (const float*)d_in[0];
    const float* W1   = (const float*)d_in[1];
    const float* b1   = (const float*)d_in[2];
    const float* W2   = (const float*)d_in[3];
    const float* b2   = (const float*)d_in[4];
    const float* aux  = (const float*)d_in[5];
    const float* clfW = (const float*)d_in[6];
    const float* clfb = (const float*)d_in[7];
    const int*   ei   = (const int*)d_in[8];
    float* out = (float*)d_out;
    char* ws = (char*)d_ws;

    __half* hbufH = (__half*)(ws + 0);           // 1,536,000
    __half* h1H   = (__half*)(ws + 1536000);     // 1,536,000
    __half* h2H   = (__half*)(ws + 3072000);     // 1,536,000
    float*  score = (float*)(ws + 4608000);      // 48,000
    int*    csrc  = (int*)  (ws + 4656000);      // 4,608,000
    int*    cur   = (int*)  (ws + 9264000);      // 1,536,000 (padded lines)
    double* M8    = (double*)(ws + 10800000);    // 66,560
    unsigned short* w1Th = (unsigned short*)(ws + 10866560);  // 65,536
    unsigned short* w1Tl = (unsigned short*)(ws + 10932096);  // 65,536

    init_k<<<128, 256, 0, stream>>>(W1, w1Th, w1Tl, cur, M8);
    k1_gemm_fill<<<GEMM_BLKS + FILL_BLKS, 256, 0, stream>>>(x, w1Th, w1Tl, ei,
                                                            hbufH, cur, csrc);
    agg1_k<<<N_NODES / 2, 256, 0, stream>>>(hbufH, b1, cur, csrc, h1H);
    agg2_k<<<N_NODES / 2, 256, 0, stream>>>(h1H, W2, b2, aux, cur, csrc, h2H, score);
    momden_k<<<MOM_BLKS, 256, 0, stream>>>(h2H, score, M8);
    final_k<<<750, 256, 0, stream>>>(h2H, score, M8, clfW, clfb, out);
}

// Round 27
// 86.754 us; speedup vs baseline: 1.0746x; 1.0746x over previous
//
#include <hip/hip_runtime.h>
#include <hip/hip_bf16.h>
#include <hip/hip_fp16.h>

#define N_NODES 12000
#define N_EDGES 384000
#define F_IN 512
#define H 64
#define C_CLS 7
#define KTERMS 16
#define PAD 96
#define CSTR 32      // cur stride (ints): one 128B line per node (fill contention-free)
#define MOM_BLKS 768
#define MSTR 1040    // doubles per M copy: 1024 M + 16 m0
#define NB 4         // nodes per agg block (1 per wave)
#define GEMM_BLKS 188   // 188 x 64-row MFMA tiles (12032 >= 12000, guarded)
#define FILL_BLKS 324

typedef __attribute__((ext_vector_type(8))) short bf16x8;
typedef __attribute__((ext_vector_type(4))) float f32x4;

__device__ __forceinline__ float wred_f(float x) {
    #pragma unroll
    for (int o = 32; o > 0; o >>= 1) x += __shfl_xor(x, o);
    return x;
}

// ---------------- k0: W1 -> transposed bf16 hi/lo split; zero cur lines + M8
__global__ __launch_bounds__(256) void init_k(const float* __restrict__ W1,
                                              unsigned short* __restrict__ w1Th,
                                              unsigned short* __restrict__ w1Tl,
                                              int* __restrict__ cur,
                                              double* __restrict__ M8) {
    int i = blockIdx.x * 256 + threadIdx.x;    // 128*256 = 32768 threads
    if (i < 64 * 512) {
        int n = i >> 9, k = i & 511;
        float v = W1[k * 64 + n];              // W1T[n][k] = W1[k][n]
        unsigned xb = __float_as_uint(v);
        float hf = __uint_as_float(xb & 0xffff0000u);
        w1Th[i] = (unsigned short)(xb >> 16);
        w1Tl[i] = (unsigned short)(__float_as_uint(v - hf) >> 16);
    }
    if (i < N_NODES) cur[i * CSTR] = 0;
    if (i < 8 * MSTR) M8[i] = 0.0;
}

// ---------------- k1: gemm1 via bf16-split MFMA; OUTPUT IN FP16 || CSR fill
__global__ __launch_bounds__(256) void k1_gemm_fill(const float* __restrict__ x,
                                                    const unsigned short* __restrict__ w1Th,
                                                    const unsigned short* __restrict__ w1Tl,
                                                    const int* __restrict__ ei,
                                                    __half* __restrict__ hbufH,
                                                    int* __restrict__ cur,
                                                    int* __restrict__ csrc) {
    const int b = blockIdx.x, t = threadIdx.x;
    if (b < GEMM_BLKS) {
        __shared__ unsigned short wh[64 * 72];    // [n][k-chunk 64], stride 72 shorts
        __shared__ unsigned short wl[64 * 72];
        const int l = t & 63, w = t >> 6;
        const int lm = l & 15, lk = l >> 4;
        const int i0 = b * 64;
        const int arow = min(i0 + w * 16 + lm, N_NODES - 1);
        const float* xrow = x + (size_t)arow * F_IN;
        f32x4 acc[4];
        #pragma unroll
        for (int c = 0; c < 4; ++c) acc[c] = (f32x4){0.f, 0.f, 0.f, 0.f};
        for (int kc = 0; kc < 8; ++kc) {
            #pragma unroll
            for (int q = 0; q < 2; ++q) {
                int idx = t + q * 256;
                int n = idx >> 3, kg = idx & 7;
                *(uint4*)(&wh[n * 72 + kg * 8]) =
                    *(const uint4*)(w1Th + n * 512 + kc * 64 + kg * 8);
                *(uint4*)(&wl[n * 72 + kg * 8]) =
                    *(const uint4*)(w1Tl + n * 512 + kc * 64 + kg * 8);
            }
            __syncthreads();
            #pragma unroll
            for (int ks = 0; ks < 2; ++ks) {
                float4 v0 = *(const float4*)(xrow + kc * 64 + ks * 32 + lk * 8);
                float4 v1 = *(const float4*)(xrow + kc * 64 + ks * 32 + lk * 8 + 4);
                float xv[8] = {v0.x, v0.y, v0.z, v0.w, v1.x, v1.y, v1.z, v1.w};
                bf16x8 ah, al;
                #pragma unroll
                for (int j = 0; j < 8; ++j) {
                    unsigned xb = __float_as_uint(xv[j]);
                    float hf = __uint_as_float(xb & 0xffff0000u);
                    ah[j] = (short)(xb >> 16);
                    al[j] = (short)(__float_as_uint(xv[j] - hf) >> 16);
                }
                #pragma unroll
                for (int c = 0; c < 4; ++c) {
                    bf16x8 bh = *(const bf16x8*)(&wh[(c * 16 + lm) * 72 + ks * 32 + lk * 8]);
                    bf16x8 bl = *(const bf16x8*)(&wl[(c * 16 + lm) * 72 + ks * 32 + lk * 8]);
                    acc[c] = __builtin_amdgcn_mfma_f32_16x16x32_bf16(ah, bh, acc[c], 0, 0, 0);
                    acc[c] = __builtin_amdgcn_mfma_f32_16x16x32_bf16(ah, bl, acc[c], 0, 0, 0);
                    acc[c] = __builtin_amdgcn_mfma_f32_16x16x32_bf16(al, bh, acc[c], 0, 0, 0);
                }
            }
            __syncthreads();
        }
        #pragma unroll
        for (int c = 0; c < 4; ++c) {
            #pragma unroll
            for (int r = 0; r < 4; ++r) {
                int row = i0 + w * 16 + lk * 4 + r;
                if (row < N_NODES)
                    hbufH[(size_t)row * H + c * 16 + lm] = __float2half(acc[c][r]);
            }
        }
    } else {
        for (int e = (b - GEMM_BLKS) * 256 + t; e < N_EDGES; e += FILL_BLKS * 256) {
            int s = ei[e];
            int d = ei[N_EDGES + e];
            int pos = atomicAdd(&cur[d * CSTR], 1);
            if (pos < PAD) csrc[d * PAD + pos] = s;   // overflow guard
        }
    }
}

// ---------------- k2: agg1 = relu((Â @ hbuf) + b1)   [fp16 gather, fp16 out]
__global__ __launch_bounds__(256) void agg1_k(const __half* __restrict__ hbufH,
                                              const float* __restrict__ b1,
                                              const int* __restrict__ cur,
                                              const int* __restrict__ csrc,
                                              __half* __restrict__ h1H) {
    __shared__ int2 sPair[NB * PAD];
    __shared__ int sDeg[NB];
    __shared__ float sIsd[NB];
    const int t = threadIdx.x, f = t & 63, w = t >> 6;
    const int base = blockIdx.x * NB;
    if (t < NB) {
        int d = cur[(base + t) * CSTR];
        sDeg[t] = min(d, PAD);
        sIsd[t] = rsqrtf((float)d + 1.f);
    }
    __syncthreads();
    for (int idx = t; idx < NB * PAD; idx += 256) {
        int n = idx / PAD, e = idx - n * PAD;
        if (e < sDeg[n]) {
            int s = csrc[(base + n) * PAD + e];
            sPair[idx] = make_int2(s, __float_as_int(rsqrtf((float)cur[s * CSTR] + 1.f)));
        }
    }
    __syncthreads();
    const int i = base + w;
    const int deg = sDeg[w];
    const float isd = sIsd[w];
    const int2* pp = sPair + w * PAD;
    float acc = 0.f;
    int e = 0;
    for (; e + 8 <= deg; e += 8) {
        int2 p0 = pp[e], p1 = pp[e+1], p2 = pp[e+2], p3 = pp[e+3];
        int2 p4 = pp[e+4], p5 = pp[e+5], p6 = pp[e+6], p7 = pp[e+7];
        acc += __half2float(hbufH[p0.x * H + f]) * __int_as_float(p0.y)
             + __half2float(hbufH[p1.x * H + f]) * __int_as_float(p1.y)
             + __half2float(hbufH[p2.x * H + f]) * __int_as_float(p2.y)
             + __half2float(hbufH[p3.x * H + f]) * __int_as_float(p3.y)
             + __half2float(hbufH[p4.x * H + f]) * __int_as_float(p4.y)
             + __half2float(hbufH[p5.x * H + f]) * __int_as_float(p5.y)
             + __half2float(hbufH[p6.x * H + f]) * __int_as_float(p6.y)
             + __half2float(hbufH[p7.x * H + f]) * __int_as_float(p7.y);
    }
    for (; e + 4 <= deg; e += 4) {
        int2 p0 = pp[e], p1 = pp[e+1], p2 = pp[e+2], p3 = pp[e+3];
        acc += __half2float(hbufH[p0.x * H + f]) * __int_as_float(p0.y)
             + __half2float(hbufH[p1.x * H + f]) * __int_as_float(p1.y)
             + __half2float(hbufH[p2.x * H + f]) * __int_as_float(p2.y)
             + __half2float(hbufH[p3.x * H + f]) * __int_as_float(p3.y);
    }
    for (; e < deg; ++e) {
        int2 p = pp[e];
        acc += __half2float(hbufH[p.x * H + f]) * __int_as_float(p.y);
    }
    float res = (acc + __half2float(hbufH[i * H + f]) * isd) * isd + b1[f];
    h1H[i * H + f] = __float2half(fmaxf(res, 0.f));
}

// ---------------- k3: agg2 = (Â @ h1) @ W2 + b2, + cosine score  [fp16 gather]
__global__ __launch_bounds__(256) void agg2_k(const __half* __restrict__ h1H,
                                              const float* __restrict__ W2,
                                              const float* __restrict__ b2,
                                              const float* __restrict__ aux,
                                              const int* __restrict__ cur,
                                              const int* __restrict__ csrc,
                                              float* __restrict__ h2,
                                              float* __restrict__ score) {
    __shared__ float w2s[64 * 64];
    __shared__ int2 sPair[NB * PAD];
    __shared__ int sDeg[NB];
    __shared__ float sIsd[NB];
    __shared__ float anorm[64];
    __shared__ float gsh[NB * 64];
    const int t = threadIdx.x, f = t & 63, w = t >> 6;
    const int base = blockIdx.x * NB;
    #pragma unroll
    for (int q = 0; q < 4; ++q) {
        int idx = t + q * 256;
        int r = idx >> 4, c4 = idx & 15;
        *(float4*)(&w2s[r * 64 + c4 * 4]) = *(const float4*)(W2 + r * H + c4 * 4);
    }
    if (t < NB) {
        int d = cur[(base + t) * CSTR];
        sDeg[t] = min(d, PAD);
        sIsd[t] = rsqrtf((float)d + 1.f);
    }
    if (t < 64) {
        float av = aux[t];
        anorm[t] = av * rsqrtf(fmaxf(wred_f(av * av), 1e-24f));
    }
    __syncthreads();
    for (int idx = t; idx < NB * PAD; idx += 256) {
        int n = idx / PAD, e = idx - n * PAD;
        if (e < sDeg[n]) {
            int s = csrc[(base + n) * PAD + e];
            sPair[idx] = make_int2(s, __float_as_int(rsqrtf((float)cur[s * CSTR] + 1.f)));
        }
    }
    __syncthreads();
    const int i = base + w;
    const int deg = sDeg[w];
    const float isd = sIsd[w];
    const int2* pp = sPair + w * PAD;
    float acc = 0.f;
    int e = 0;
    for (; e + 8 <= deg; e += 8) {
        int2 p0 = pp[e], p1 = pp[e+1], p2 = pp[e+2], p3 = pp[e+3];
        int2 p4 = pp[e+4], p5 = pp[e+5], p6 = pp[e+6], p7 = pp[e+7];
        acc += __half2float(h1H[p0.x * H + f]) * __int_as_float(p0.y)
             + __half2float(h1H[p1.x * H + f]) * __int_as_float(p1.y)
             + __half2float(h1H[p2.x * H + f]) * __int_as_float(p2.y)
             + __half2float(h1H[p3.x * H + f]) * __int_as_float(p3.y)
             + __half2float(h1H[p4.x * H + f]) * __int_as_float(p4.y)
             + __half2float(h1H[p5.x * H + f]) * __int_as_float(p5.y)
             + __half2float(h1H[p6.x * H + f]) * __int_as_float(p6.y)
             + __half2float(h1H[p7.x * H + f]) * __int_as_float(p7.y);
    }
    for (; e + 4 <= deg; e += 4) {
        int2 p0 = pp[e], p1 = pp[e+1], p2 = pp[e+2], p3 = pp[e+3];
        acc += __half2float(h1H[p0.x * H + f]) * __int_as_float(p0.y)
             + __half2float(h1H[p1.x * H + f]) * __int_as_float(p1.y)
             + __half2float(h1H[p2.x * H + f]) * __int_as_float(p2.y)
             + __half2float(h1H[p3.x * H + f]) * __int_as_float(p3.y);
    }
    for (; e < deg; ++e) {
        int2 p = pp[e];
        acc += __half2float(h1H[p.x * H + f]) * __int_as_float(p.y);
    }
    float g = (acc + __half2float(h1H[i * H + f]) * isd) * isd;
    gsh[w * 64 + f] = g;
    __builtin_amdgcn_wave_barrier();
    float hv = b2[f];
    #pragma unroll 16
    for (int k = 0; k < 64; ++k) hv += gsh[w * 64 + k] * w2s[k * 64 + f];
    h2[i * H + f] = hv;
    float dp = wred_f(hv * anorm[f]);
    float nn = wred_f(hv * hv);
    if (f == 0) score[i] = dp / fmaxf(sqrtf(nn), 1e-8f);
}

// ---------------- k4: moments, 768 blocks, striped 8-copy atomic flush
__global__ __launch_bounds__(256) void momden_k(const float* __restrict__ h2,
                                                const float* __restrict__ score,
                                                double* __restrict__ M8) {
    const int t = threadIdx.x, f = t & 63, g = t >> 6;
    float accM[KTERMS], accD[KTERMS];
    #pragma unroll
    for (int k = 0; k < KTERMS; ++k) { accM[k] = 0.f; accD[k] = 0.f; }
    for (int j = blockIdx.x * 4 + g; j < N_NODES; j += MOM_BLKS * 4) {
        float sj = score[j];
        float wj = expf(-sj * sj);
        float hv = h2[j * H + f];
        float tm = wj * hv, td = wj;
        #pragma unroll
        for (int k = 0; k < KTERMS; ++k) {
            accM[k] += tm; tm *= sj;
            accD[k] += td; td *= sj;
        }
    }
    __shared__ float Msh[4 * KTERMS * 64];
    __shared__ float Dsh[4 * KTERMS];
    #pragma unroll
    for (int k = 0; k < KTERMS; ++k) Msh[(g * KTERMS + k) * 64 + f] = accM[k];
    if (f == 0) {
        #pragma unroll
        for (int k = 0; k < KTERMS; ++k) Dsh[g * KTERMS + k] = accD[k];
    }
    __syncthreads();
    double* Mc = M8 + (size_t)(blockIdx.x & 7) * MSTR;
    for (int idx = t; idx < KTERMS * 64; idx += 256) {
        int k = idx >> 6, ff = idx & 63;
        float sum = Msh[(0 * KTERMS + k) * 64 + ff] + Msh[(1 * KTERMS + k) * 64 + ff]
                  + Msh[(2 * KTERMS + k) * 64 + ff] + Msh[(3 * KTERMS + k) * 64 + ff];
        unsafeAtomicAdd(&Mc[idx], (double)sum);
    }
    if (t < KTERMS) {
        float sum = Dsh[t] + Dsh[KTERMS + t] + Dsh[2 * KTERMS + t] + Dsh[3 * KTERMS + t];
        unsafeAtomicAdd(&Mc[1024 + t], (double)sum);
    }
}

// ---------------- k5: z + concat classifier (sums the 8 M copies)
__global__ __launch_bounds__(256) void final_k(const float* __restrict__ h2,
                                               const float* __restrict__ score,
                                               const double* __restrict__ M8,
                                               const float* __restrict__ clfW,
                                               const float* __restrict__ clfb,
                                               float* __restrict__ out) {
    __shared__ float Ms[KTERMS * 64];
    __shared__ float m0s[KTERMS];
    __shared__ float cw[128 * C_CLS];
    __shared__ float cb[8];
    __shared__ float zh[4 * 128];
    const int t = threadIdx.x, f = t & 63, w = t >> 6;
    for (int idx = t; idx < KTERMS * 64; idx += 256) {
        double s = 0.0;
        #pragma unroll
        for (int c = 0; c < 8; ++c) s += M8[(size_t)c * MSTR + idx];
        Ms[idx] = (float)s;
    }
    if (t < KTERMS) {
        double s = 0.0;
        #pragma unroll
        for (int c = 0; c < 8; ++c) s += M8[(size_t)c * MSTR + 1024 + t];
        m0s[t] = (float)s;
    }
    for (int idx = t; idx < 128 * C_CLS; idx += 256) cw[idx] = clfW[idx];
    if (t < C_CLS) cb[t] = clfb[t];
    __syncthreads();
    const int base = blockIdx.x * 16;
    for (int q = 0; q < 4; ++q) {
        int i = base + q * 4 + w;
        float s = score[i];
        float c = expf(-s * s);
        float t2 = 2.f * s;
        float num = 0.f, den = 0.f;
        #pragma unroll
        for (int k = 0; k < KTERMS; ++k) {
            num += c * Ms[k * 64 + f];
            den += c * m0s[k];
            c *= t2 * (1.0f / (float)(k + 1));
        }
        zh[w * 128 + f] = h2[i * H + f];
        zh[w * 128 + 64 + f] = num / den;
        __builtin_amdgcn_wave_barrier();
        if (f < C_CLS) {
            float o = cb[f];
            #pragma unroll 8
            for (int u = 0; u < 128; ++u) o += zh[w * 128 + u] * cw[u * C_CLS + f];
            out[(size_t)i * C_CLS + f] = o;
        }
        __builtin_amdgcn_wave_barrier();
    }
}

// ---------------- launch
extern "C" void kernel_launch(void* const* d_in, const int* in_sizes, int n_in,
                              void* d_out, int out_size, void* d_ws, size_t ws_size,
                              hipStream_t stream) {
    (void)in_sizes; (void)n_in; (void)out_size; (void)ws_size;
    const float* x    = (const float*)d_in[0];
    const float* W1   = (const float*)d_in[1];
    const float* b1   = (const float*)d_in[2];
    const float* W2   = (const float*)d_in[3];
    const float* b2   = (const float*)d_in[4];
    const float* aux  = (const float*)d_in[5];
    const float* clfW = (const float*)d_in[6];
    const float* clfb = (const float*)d_in[7];
    const int*   ei   = (const int*)d_in[8];
    float* out = (float*)d_out;
    char* ws = (char*)d_ws;

    __half* hbufH = (__half*)(ws + 0);           // 1,536,000
    __half* h1H   = (__half*)(ws + 1536000);     // 1,536,000
    float*  h2    = (float*)(ws + 3072000);      // 3,072,000
    float*  score = (float*)(ws + 6144000);      // 48,000
    int*    csrc  = (int*)  (ws + 6192000);      // 4,608,000
    int*    cur   = (int*)  (ws + 10800000);     // 1,536,000 (padded lines)
    double* M8    = (double*)(ws + 12336000);    // 66,560
    unsigned short* w1Th = (unsigned short*)(ws + 12402560);  // 65,536
    unsigned short* w1Tl = (unsigned short*)(ws + 12468096);  // 65,536

    init_k<<<128, 256, 0, stream>>>(W1, w1Th, w1Tl, cur, M8);
    k1_gemm_fill<<<GEMM_BLKS + FILL_BLKS, 256, 0, stream>>>(x, w1Th, w1Tl, ei,
                                                            hbufH, cur, csrc);
    agg1_k<<<N_NODES / NB, 256, 0, stream>>>(hbufH, b1, cur, csrc, h1H);
    agg2_k<<<N_NODES / NB, 256, 0, stream>>>(h1H, W2, b2, aux, cur, csrc, h2, score);
    momden_k<<<MOM_BLKS, 256, 0, stream>>>(h2, score, M8);
    final_k<<<750, 256, 0, stream>>>(h2, score, M8, clfW, clfb, out);
}